// Round 13
// baseline (344.234 us; speedup 1.0000x reference)
//
#include <hip/hip_runtime.h>

#define NN 80000
#define NE 1280000
#define NGR 8
#define BN_EPS 1e-3f
#define NBF 625     // fine dst-buckets (128 nodes each; 625*128 == NN)
#define GB 512      // blocks for bhist/bfill
#define CHK 2500    // edges per block (GB*CHK == NE)

typedef unsigned short ushort;
typedef __attribute__((ext_vector_type(8))) short bf16x8;
typedef __attribute__((ext_vector_type(4))) float f32x4;

// ---------------- order-preserving float <-> unsigned encoding ----------------
__device__ __forceinline__ unsigned enc_f(float f) {
    unsigned b = __float_as_uint(f);
    return (f >= 0.f) ? (b | 0x80000000u) : ~b;
}
__device__ __forceinline__ float dec_f(unsigned u) {
    return (u & 0x80000000u) ? __uint_as_float(u & 0x7FFFFFFFu) : __uint_as_float(~u);
}
// fp32 -> bf16 (round-to-nearest-even)
__device__ __forceinline__ ushort f2bf(float f) {
    unsigned u = __float_as_uint(f);
    unsigned r = u + 0x7FFFu + ((u >> 16) & 1u);
    return (ushort)(r >> 16);
}
// 8 bf16 (16B) fused-multiply-accumulate into fp32 acc[8]
__device__ __forceinline__ void fma8(float* acc, const ushort* p, float w) {
    uint4 q = *(const uint4*)p;
    acc[0] += w * __uint_as_float((q.x & 0xFFFFu) << 16);
    acc[1] += w * __uint_as_float(q.x & 0xFFFF0000u);
    acc[2] += w * __uint_as_float((q.y & 0xFFFFu) << 16);
    acc[3] += w * __uint_as_float(q.y & 0xFFFF0000u);
    acc[4] += w * __uint_as_float((q.z & 0xFFFFu) << 16);
    acc[5] += w * __uint_as_float(q.z & 0xFFFF0000u);
    acc[6] += w * __uint_as_float((q.w & 0xFFFFu) << 16);
    acc[7] += w * __uint_as_float(q.w & 0xFFFF0000u);
}

// ================= CSR build: counting sort w/ precomputed bases =================
__global__ __launch_bounds__(256) void k_bhist(const int* __restrict__ dst,
                                               int* __restrict__ hcnt) {
    __shared__ int lh[NBF];
    for (int i = threadIdx.x; i < NBF; i += 256) lh[i] = 0;
    __syncthreads();
    int e0 = blockIdx.x * CHK;
    for (int e = e0 + threadIdx.x; e < e0 + CHK; e += 256)
        atomicAdd(&lh[dst[e] >> 7], 1);
    __syncthreads();
    int* row = hcnt + (size_t)blockIdx.x * NBF;
    for (int i = threadIdx.x; i < NBF; i += 256) row[i] = lh[i];
}

// per-bin exclusive scan across GB blocks (in-place) + bin totals.
// LAST block additionally: scan totals -> bo, bf16 weight prep, MXE zero.
__global__ __launch_bounds__(256) void k_bbase1m(int* __restrict__ hcnt,
                                                 int* __restrict__ tot,
                                                 int* __restrict__ done,
                                                 int* __restrict__ bo,
                                                 const float* __restrict__ W2,
                                                 const float* __restrict__ W4,
                                                 ushort* __restrict__ W2t,
                                                 ushort* __restrict__ W4t,
                                                 unsigned* __restrict__ mxe1) {
    __shared__ int sm[256];
    __shared__ int lastflag;
    int bin = blockIdx.x, t = threadIdx.x;
    int v[2];
    int s = 0;
    #pragma unroll
    for (int j = 0; j < 2; ++j) {
        v[j] = hcnt[(size_t)(t * 2 + j) * NBF + bin];
        s += v[j];
    }
    sm[t] = s;
    __syncthreads();
    #pragma unroll
    for (int off = 1; off < 256; off <<= 1) {
        int u = (t >= off) ? sm[t - off] : 0;
        __syncthreads();
        sm[t] += u;
        __syncthreads();
    }
    int run = sm[t] - s;
    if (t == 255) tot[bin] = sm[255];
    #pragma unroll
    for (int j = 0; j < 2; ++j) {
        hcnt[(size_t)(t * 2 + j) * NBF + bin] = run;
        run += v[j];
    }
    // ---- last-block merge of the totals scan + weight prep ----
    __threadfence();
    if (t == 0) lastflag = (atomicAdd(done, 1) == NBF - 1) ? 1 : 0;
    __syncthreads();
    if (!lastflag) return;
    __threadfence();
    int v3[3], ss = 0;
    #pragma unroll
    for (int j = 0; j < 3; ++j) {
        int idx = t * 3 + j;
        v3[j] = (idx < NBF) ? tot[idx] : 0;
        ss += v3[j];
    }
    __syncthreads();
    sm[t] = ss;
    __syncthreads();
    #pragma unroll
    for (int off = 1; off < 256; off <<= 1) {
        int u = (t >= off) ? sm[t - off] : 0;
        __syncthreads();
        sm[t] += u;
        __syncthreads();
    }
    int run2 = sm[t] - ss;
    #pragma unroll
    for (int j = 0; j < 3; ++j) {
        int idx = t * 3 + j;
        if (idx < NBF) bo[idx] = run2;
        run2 += v3[j];
    }
    if (t == 0) bo[NBF] = NE;
    #pragma unroll
    for (int j = 0; j < 4; ++j) {
        int i = t + j * 256;
        int f = i >> 5, k = i & 31;
        W2t[i] = f2bf(W2[k * 32 + f]);
    }
    #pragma unroll
    for (int j = 0; j < 16; ++j) {
        int i = t + j * 256;
        int f = i >> 6, k = i & 63;
        W4t[i] = f2bf(W4[k * 64 + f]);
    }
    mxe1[t] = 0u; mxe1[t + 256] = 0u; mxe1[t + 512] = 0u;   // MXE1+MXE2
}

// Pass C: bucket edges. In-LDS counting sort by bucket, then coalesced run
// writes. No global atomics. Payload: src(17b) | g(3b,@17) | dlow(7b,@20)
__global__ __launch_bounds__(256) void k_bfill(const int* __restrict__ src,
                                               const int* __restrict__ dst,
                                               const float* __restrict__ ew,
                                               const int* __restrict__ ids,
                                               const int* __restrict__ hcnt,
                                               const int* __restrict__ bo,
                                               int2* __restrict__ cB) {
    __shared__ int lh[NBF];
    __shared__ int delta[NBF];
    __shared__ int lcur[NBF];
    __shared__ int2 srt[CHK];
    __shared__ short sbin[CHK];
    __shared__ int sm[256];
    int t = threadIdx.x;
    int e0 = blockIdx.x * CHK;
    const int* row = hcnt + (size_t)blockIdx.x * NBF;
    for (int i = t; i < NBF; i += 256) lh[i] = 0;
    __syncthreads();
    for (int e = e0 + t; e < e0 + CHK; e += 256)
        atomicAdd(&lh[dst[e] >> 7], 1);
    __syncthreads();
    int c0, c1, c2;
    {
        int i0 = t * 3, i1 = t * 3 + 1, i2 = t * 3 + 2;
        c0 = (i0 < NBF) ? lh[i0] : 0;
        c1 = (i1 < NBF) ? lh[i1] : 0;
        c2 = (i2 < NBF) ? lh[i2] : 0;
    }
    int ssum = c0 + c1 + c2;
    sm[t] = ssum;
    __syncthreads();
    #pragma unroll
    for (int off = 1; off < 256; off <<= 1) {
        int u = (t >= off) ? sm[t - off] : 0;
        __syncthreads();
        sm[t] += u;
        __syncthreads();
    }
    {
        int run = sm[t] - ssum;
        int i0 = t * 3;
        #pragma unroll
        for (int j = 0; j < 3; ++j) {
            int idx = i0 + j;
            int cnt = (j == 0) ? c0 : (j == 1) ? c1 : c2;
            if (idx < NBF) {
                lh[idx] = run;
                delta[idx] = row[idx] + bo[idx] - run;
                lcur[idx] = 0;
            }
            run += cnt;
        }
    }
    __syncthreads();
    for (int e = e0 + t; e < e0 + CHK; e += 256) {
        int d = dst[e];
        int s = src[e];
        int bin = d >> 7;
        int r = atomicAdd(&lcur[bin], 1);
        int slot = lh[bin] + r;
        srt[slot] = make_int2(s | (ids[s] << 17) | ((d & 127) << 20),
                              __float_as_int(ew[e]));
        sbin[slot] = (short)bin;
    }
    __syncthreads();
    for (int p = t; p < CHK; p += 256)
        cB[delta[sbin[p]] + p] = srt[p];
}

// Pass D + fused gSX: sort bucket by dlow -> rp,cE; then L2-hot S/AX gather
__global__ __launch_bounds__(512) void k_insort(const int* __restrict__ bo,
                                                const int2* __restrict__ cB,
                                                const float* __restrict__ x,
                                                int* __restrict__ rp,
                                                int2* __restrict__ cE,
                                                float* __restrict__ S,
                                                float* __restrict__ AX) {
    __shared__ int lc[128];
    __shared__ int loff[128];
    __shared__ int sm[512];
    int bin = blockIdx.x, t = threadIdx.x;
    int s0 = bo[bin], s1 = bo[bin + 1];
    if (t < 128) lc[t] = 0;
    __syncthreads();
    for (int i = s0 + t; i < s1; i += 512)
        atomicAdd(&lc[(cB[i].x >> 20) & 127], 1);
    __syncthreads();
    int v = (t < 128) ? lc[t] : 0;
    sm[t] = v;
    __syncthreads();
    #pragma unroll
    for (int off = 1; off < 128; off <<= 1) {
        int u = (t >= off && t < 128) ? sm[t - off] : 0;
        __syncthreads();
        if (t < 128) sm[t] += u;
        __syncthreads();
    }
    if (t < 128) {
        loff[t] = sm[t] - v;
        rp[bin * 128 + t] = s0 + loff[t];
        lc[t] = 0;
    }
    if (bin == NBF - 1 && t == 0) rp[NN] = NE;
    __syncthreads();
    for (int i = s0 + t; i < s1; i += 512) {
        int2 a = cB[i];
        int dlow = (a.x >> 20) & 127;
        int pos = s0 + loff[dlow] + atomicAdd(&lc[dlow], 1);
        cE[pos] = make_int2((a.x & 0x1FFFF) | (((a.x >> 17) & 7) << 24), a.y);
    }
    __syncthreads();
    int n = t >> 2, q = t & 3;
    int ne0 = s0 + loff[n];
    int ne1 = ne0 + lc[n];
    float sv[8] = {0, 0, 0, 0, 0, 0, 0, 0};
    float ax0 = 0.f, ax1 = 0.f, ax2 = 0.f;
    for (int i = ne0 + q; i < ne1; i += 4) {
        int2 a = cE[i];
        float w = __int_as_float(a.y);
        int s = a.x & 0xFFFFFF;
        int gg = a.x >> 24;
        #pragma unroll
        for (int g = 0; g < 8; ++g) sv[g] += (gg == g) ? w : 0.f;
        const float* xp = x + s * 3;
        ax0 += w * xp[0]; ax1 += w * xp[1]; ax2 += w * xp[2];
    }
    #pragma unroll
    for (int g = 0; g < 8; ++g) {
        sv[g] += __shfl_xor(sv[g], 1);
        sv[g] += __shfl_xor(sv[g], 2);
    }
    ax0 += __shfl_xor(ax0, 1); ax0 += __shfl_xor(ax0, 2);
    ax1 += __shfl_xor(ax1, 1); ax1 += __shfl_xor(ax1, 2);
    ax2 += __shfl_xor(ax2, 1); ax2 += __shfl_xor(ax2, 2);
    if (q == 0) {
        int node = bin * 128 + n;
        float4* Sp = (float4*)(S + (size_t)node * 8);
        Sp[0] = make_float4(sv[0], sv[1], sv[2], sv[3]);
        Sp[1] = make_float4(sv[4], sv[5], sv[6], sv[7]);
        *(float4*)(AX + (size_t)node * 4) = make_float4(ax0, ax1, ax2, 0.f);
    }
}

// ======== layer 1+2 fully fused: per-edge on-the-fly h1 from AX (L2-hot),
// aggregate in regs, MFMA @W2 per node, BN+pool epilogue -> MXE1 ========
__global__ __launch_bounds__(256) void k_gpl2(const float* __restrict__ AX,
                                              const float* __restrict__ W1,
                                              const float* __restrict__ b1,
                                              const ushort* __restrict__ W2t,
                                              const int* __restrict__ rp,
                                              const int2* __restrict__ cE,
                                              const int* __restrict__ ids,
                                              const float* __restrict__ b2,
                                              const float* __restrict__ g1,
                                              const float* __restrict__ be1,
                                              const float* __restrict__ m1,
                                              const float* __restrict__ v1,
                                              unsigned* __restrict__ mxe) {
    __shared__ unsigned lmx[NGR * 32];
    __shared__ ushort aggS[64 * 40];
    __shared__ int gids[64];
    int t = threadIdx.x;
    int nb = blockIdx.x * 64;
    lmx[t] = 0u;
    if (t < 64) gids[t] = ids[nb + t];
    int c = t & 3;
    float w1r0[8], w1r1[8], w1r2[8], b1c[8];
    #pragma unroll
    for (int j = 0; j < 8; ++j) {
        int f = c * 8 + j;
        w1r0[j] = W1[f]; w1r1[j] = W1[32 + f]; w1r2[j] = W1[64 + f];
        b1c[j] = b1[f];
    }
    int nl = t >> 2;
    int n = nb + nl;
    int e0 = rp[n], e1 = rp[n + 1];
    float acc[8] = {0, 0, 0, 0, 0, 0, 0, 0};
    for (int i = e0; i < e1; ++i) {
        int2 a = cE[i];
        float w = __int_as_float(a.y);
        float axv = AX[(size_t)(a.x & 0xFFFFFF) * 4 + c];
        float a0 = __shfl(axv, 0, 4);
        float a1 = __shfl(axv, 1, 4);
        float a2 = __shfl(axv, 2, 4);
        #pragma unroll
        for (int j = 0; j < 8; ++j) {
            float pre = b1c[j] + a0 * w1r0[j] + a1 * w1r1[j] + a2 * w1r2[j];
            acc[j] += w * fmaxf(pre, 0.f);
        }
    }
    #pragma unroll
    for (int j = 0; j < 8; ++j) aggS[nl * 40 + c * 8 + j] = f2bf(acc[j]);
    __syncthreads();
    int lane = t & 63, wave = t >> 6;
    int quad = lane >> 4, col = lane & 15;
    bf16x8 afr = *(const bf16x8*)(aggS + (wave * 16 + col) * 40 + quad * 8);
    #pragma unroll
    for (int nt = 0; nt < 2; ++nt) {
        bf16x8 bfr = *(const bf16x8*)(W2t + (nt * 16 + col) * 32 + quad * 8);
        f32x4 d = {0.f, 0.f, 0.f, 0.f};
        d = __builtin_amdgcn_mfma_f32_16x16x32_bf16(afr, bfr, d, 0, 0, 0);
        int f = nt * 16 + col;
        float scale = g1[f] * rsqrtf(v1[f] + BN_EPS);
        float bb = b2[f], mm = m1[f], bee = be1[f];
        #pragma unroll
        for (int r = 0; r < 4; ++r) {
            int node_l = wave * 16 + quad * 4 + r;
            float h = fmaxf(d[r] + bb, 0.f);
            float val = (h - mm) * scale + bee;
            atomicMax(&lmx[gids[node_l] * 32 + f], enc_f(val));
        }
    }
    __syncthreads();
    {
        unsigned u = lmx[t];
        if (u) atomicMax(&mxe[t], u);
    }
}

// ======== MFMA fused l3+l4 (+ integrated dechw3):
// HW3 = dec(MXE1)@W3 per block; tmp4 -> FEATURE-SLICED Tq[q][node][16] ========
__global__ __launch_bounds__(256) void k_l34m(const float* __restrict__ S,
                                              const unsigned* __restrict__ mxe,
                                              const float* __restrict__ W3,
                                              const float* __restrict__ b3,
                                              const ushort* __restrict__ W4t,
                                              ushort* __restrict__ T) {
    __shared__ float smxs[256];
    __shared__ float HW3s[512];
    __shared__ ushort h3s[64 * 72];
    int t = threadIdx.x;
    int nb = blockIdx.x * 64;
    smxs[t] = mxe[t] ? dec_f(mxe[t]) : 0.f;
    __syncthreads();
    {
        #pragma unroll
        for (int j = 0; j < 2; ++j) {
            int i = t + j * 256;
            int g = i >> 6, f = i & 63;
            float acc = 0.f;
            #pragma unroll
            for (int k = 0; k < 32; ++k) acc += smxs[g * 32 + k] * W3[k * 64 + f];
            HW3s[i] = acc;
        }
    }
    __syncthreads();
    {
        int f = t & 63, rr = t >> 6;
        float hwc[8];
        #pragma unroll
        for (int g = 0; g < 8; ++g) hwc[g] = HW3s[g * 64 + f];
        float bb = b3[f];
        #pragma unroll
        for (int i = 0; i < 16; ++i) {
            int n = rr + i * 4;
            const float4* sp = (const float4*)(S + (size_t)(nb + n) * 8);
            float4 s0 = sp[0], s1 = sp[1];
            float acc = bb + s0.x * hwc[0] + s0.y * hwc[1] + s0.z * hwc[2] +
                        s0.w * hwc[3] + s1.x * hwc[4] + s1.y * hwc[5] +
                        s1.z * hwc[6] + s1.w * hwc[7];
            h3s[n * 72 + f] = f2bf(fmaxf(acc, 0.f));
        }
    }
    __syncthreads();
    int lane = t & 63, wave = t >> 6;
    int quad = lane >> 4, col = lane & 15;
    int mtile = wave;
    bf16x8 a0 = *(const bf16x8*)(h3s + (mtile * 16 + col) * 72 + quad * 8);
    bf16x8 a1 = *(const bf16x8*)(h3s + (mtile * 16 + col) * 72 + 32 + quad * 8);
    #pragma unroll
    for (int ntile = 0; ntile < 4; ++ntile) {
        bf16x8 b0 = *(const bf16x8*)(W4t + (ntile * 16 + col) * 64 + quad * 8);
        bf16x8 b1v = *(const bf16x8*)(W4t + (ntile * 16 + col) * 64 + 32 + quad * 8);
        f32x4 acc = {0.f, 0.f, 0.f, 0.f};
        acc = __builtin_amdgcn_mfma_f32_16x16x32_bf16(a0, b0, acc, 0, 0, 0);
        acc = __builtin_amdgcn_mfma_f32_16x16x32_bf16(a1, b1v, acc, 0, 0, 0);
        ushort* Tq = T + (size_t)ntile * NN * 16;
        #pragma unroll
        for (int r = 0; r < 4; ++r) {
            int node = nb + mtile * 16 + quad * 4 + r;
            Tq[(size_t)node * 16 + col] = f2bf(acc[r]);
        }
    }
}

// ---- pool over feature-sliced T: 4 internal passes, each gathering from a
// 2.56 MB (L2-resident) slice; cE re-reads L1-hot. 128 nodes/block, 2 thr/node.
__global__ __launch_bounds__(256) void k_gpool4(const ushort* __restrict__ T,
                                                const int* __restrict__ rp,
                                                const int2* __restrict__ cE,
                                                const int* __restrict__ ids,
                                                const float* __restrict__ b,
                                                const float* __restrict__ g,
                                                const float* __restrict__ be,
                                                const float* __restrict__ m,
                                                const float* __restrict__ v,
                                                unsigned* __restrict__ mxe) {
    __shared__ unsigned lmx[NGR * 16];
    int t = threadIdx.x;
    int c = t & 1, nl = t >> 1;
    int n = blockIdx.x * 128 + nl;
    int e0 = rp[n], e1 = rp[n + 1];
    int gg = ids[n];
    for (int q = 0; q < 4; ++q) {
        if (t < 128) lmx[t] = 0u;
        __syncthreads();
        const ushort* tq = T + (size_t)q * NN * 16 + (c << 3);
        float a0[8] = {0, 0, 0, 0, 0, 0, 0, 0};
        float a1[8] = {0, 0, 0, 0, 0, 0, 0, 0};
        float a2[8] = {0, 0, 0, 0, 0, 0, 0, 0};
        float a3[8] = {0, 0, 0, 0, 0, 0, 0, 0};
        int i = e0;
        for (; i + 4 <= e1; i += 4) {
            int2 q0 = cE[i], q1 = cE[i + 1], q2 = cE[i + 2], q3 = cE[i + 3];
            fma8(a0, tq + ((size_t)(q0.x & 0xFFFFFF) << 4), __int_as_float(q0.y));
            fma8(a1, tq + ((size_t)(q1.x & 0xFFFFFF) << 4), __int_as_float(q1.y));
            fma8(a2, tq + ((size_t)(q2.x & 0xFFFFFF) << 4), __int_as_float(q2.y));
            fma8(a3, tq + ((size_t)(q3.x & 0xFFFFFF) << 4), __int_as_float(q3.y));
        }
        for (; i < e1; ++i) {
            int2 q0 = cE[i];
            fma8(a0, tq + ((size_t)(q0.x & 0xFFFFFF) << 4), __int_as_float(q0.y));
        }
        #pragma unroll
        for (int j = 0; j < 8; ++j) {
            int fl = (c << 3) + j;           // 0..15 within slice
            int f = (q << 4) + fl;           // global feature
            float scale = g[f] * rsqrtf(v[f] + BN_EPS);
            float h = fmaxf((a0[j] + a1[j]) + (a2[j] + a3[j]) + b[f], 0.f);
            float val = (h - m[f]) * scale + be[f];
            atomicMax(&lmx[gg * 16 + fl], enc_f(val));
        }
        __syncthreads();
        if (t < 128) {
            unsigned u = lmx[t];
            if (u) atomicMax(&mxe[(t >> 4) * 64 + (q << 4) + (t & 15)], u);
        }
        __syncthreads();
    }
}

// ---- out = softmax(S @ (dec(MXE2)@W5) + b5), HW5 computed per block ----
__global__ __launch_bounds__(256) void k_out(const float* __restrict__ S,
                                             const unsigned* __restrict__ mxe,
                                             const float* __restrict__ W5,
                                             const float* __restrict__ b5,
                                             float* __restrict__ out) {
    __shared__ float smxs[512];
    __shared__ float hw[160];
    __shared__ float bb[20];
    int t = threadIdx.x;
    smxs[t] = mxe[t] ? dec_f(mxe[t]) : 0.f;
    smxs[t + 256] = mxe[t + 256] ? dec_f(mxe[t + 256]) : 0.f;
    if (t < 20) bb[t] = b5[t];
    __syncthreads();
    if (t < 160) {
        int g = t / 20, c = t % 20;
        float acc = 0.f;
        #pragma unroll
        for (int k = 0; k < 64; ++k) acc += smxs[g * 64 + k] * W5[k * 20 + c];
        hw[t] = acc;
    }
    __syncthreads();
    int n = blockIdx.x * 256 + t;
    if (n >= NN) return;
    const float4* sp = (const float4*)(S + (size_t)n * 8);
    float4 s0 = sp[0], s1 = sp[1];
    float sv[8] = {s0.x, s0.y, s0.z, s0.w, s1.x, s1.y, s1.z, s1.w};
    float pre[20];
    #pragma unroll
    for (int c = 0; c < 20; ++c) {
        float acc = bb[c];
        #pragma unroll
        for (int g = 0; g < 8; ++g) acc += sv[g] * hw[g * 20 + c];
        pre[c] = acc;
    }
    float mx = pre[0];
    #pragma unroll
    for (int c = 1; c < 20; ++c) mx = fmaxf(mx, pre[c]);
    float sum = 0.f;
    #pragma unroll
    for (int c = 0; c < 20; ++c) { pre[c] = __expf(pre[c] - mx); sum += pre[c]; }
    float inv = 1.f / sum;
    #pragma unroll
    for (int c = 0; c < 20; ++c) out[n * 20 + c] = pre[c] * inv;
}

extern "C" void kernel_launch(void* const* d_in, const int* in_sizes, int n_in,
                              void* d_out, int out_size, void* d_ws, size_t ws_size,
                              hipStream_t stream) {
    const float* x   = (const float*)d_in[0];
    const float* ew  = (const float*)d_in[1];
    const int*   src = (const int*)d_in[2];
    const int*   dst = (const int*)d_in[3];
    const int*   ids = (const int*)d_in[4];
    const float* W1 = (const float*)d_in[5];  const float* b1 = (const float*)d_in[6];
    const float* W2 = (const float*)d_in[7];  const float* b2 = (const float*)d_in[8];
    const float* g1 = (const float*)d_in[9];  const float* be1 = (const float*)d_in[10];
    const float* m1 = (const float*)d_in[11]; const float* v1 = (const float*)d_in[12];
    const float* W3 = (const float*)d_in[13]; const float* b3 = (const float*)d_in[14];
    const float* W4 = (const float*)d_in[15]; const float* b4 = (const float*)d_in[16];
    const float* g2 = (const float*)d_in[17]; const float* be2 = (const float*)d_in[18];
    const float* m2 = (const float*)d_in[19]; const float* v2 = (const float*)d_in[20];
    const float* W5 = (const float*)d_in[21]; const float* b5 = (const float*)d_in[22];
    float* out = (float*)d_out;

    // workspace layout (~36 MB)
    char* p = (char*)d_ws;
    float*  S    = (float*)p;  p += (size_t)NN * 8 * 4;
    ushort* T    = (ushort*)p; p += (size_t)NN * 64 * 2;     // 4 feature slices
    float*  AX   = (float*)p;  p += (size_t)NN * 4 * 4;
    int*    rp   = (int*)p;    p += (size_t)(NN + 16) * 4;
    int*    hcnt = (int*)p;    p += (size_t)GB * NBF * 4;    // 1.28 MB
    int*    tot  = (int*)p;    p += 1024 * 4;
    int*    bo   = (int*)p;    p += 1024 * 4;
    int*    done = (int*)p;    p += 256 * 4;
    int2*   cB   = (int2*)p;   p += (size_t)NE * 8;
    int2*   cE   = (int2*)p;   p += (size_t)NE * 8;
    unsigned* MXE1 = (unsigned*)p; p += 256 * 4;
    unsigned* MXE2 = (unsigned*)p; p += 512 * 4;             // contiguous w/ MXE1
    ushort* W2t  = (ushort*)p; p += 1024 * 2;
    ushort* W4t  = (ushort*)p; p += 4096 * 2;

    const int BS = 256;
    const int gN = (NN + BS - 1) / BS;

    // ---- CSR build (no global atomics; bbase2+wprep+MXE-zero folded in) ----
    hipMemsetAsync(done, 0, 4, stream);
    hipLaunchKernelGGL(k_bhist, dim3(GB), dim3(BS), 0, stream, dst, hcnt);
    hipLaunchKernelGGL(k_bbase1m, dim3(NBF), dim3(BS), 0, stream, hcnt, tot, done,
                       bo, W2, W4, W2t, W4t, MXE1);
    hipLaunchKernelGGL(k_bfill, dim3(GB), dim3(BS), 0, stream, src, dst, ew, ids, hcnt, bo, cB);
    hipLaunchKernelGGL(k_insort, dim3(NBF), dim3(512), 0, stream, bo, cB, x, rp, cE, S, AX);

    // ---- layers 1+2 fully fused -> MXE1 ----
    hipLaunchKernelGGL(k_gpl2, dim3(NN / 64), dim3(BS), 0, stream, AX, W1, b1, W2t,
                       rp, cE, ids, b2, g1, be1, m1, v1, MXE1);

    // ---- layers 3+4: tmp4 (feature-sliced) then 4-pass L2-resident pool ----
    hipLaunchKernelGGL(k_l34m, dim3(NN / 64), dim3(BS), 0, stream, S, MXE1, W3, b3, W4t, T);
    hipLaunchKernelGGL(k_gpool4, dim3(NN / 128), dim3(BS), 0, stream, T, rp, cE, ids,
                       b4, g2, be2, m2, v2, MXE2);

    // ---- layer 5 (collapsed): out = softmax(S@(dec(MXE2)@W5)+b5) ----
    hipLaunchKernelGGL(k_out, dim3(gN), dim3(BS), 0, stream, S, MXE2, W5, b5, out);
}

// Round 14
// 238.997 us; speedup vs baseline: 1.4403x; 1.4403x over previous
//
#include <hip/hip_runtime.h>

#define NN 80000
#define NE 1280000
#define NGR 8
#define BN_EPS 1e-3f
#define NBF 625     // fine dst-buckets (128 nodes each; 625*128 == NN)
#define GB 512      // blocks for bhist/bfill
#define CHK 2500    // edges per block (GB*CHK == NE)

typedef unsigned short ushort;
typedef __attribute__((ext_vector_type(8))) short bf16x8;
typedef __attribute__((ext_vector_type(4))) float f32x4;

// ---------------- order-preserving float <-> unsigned encoding ----------------
__device__ __forceinline__ unsigned enc_f(float f) {
    unsigned b = __float_as_uint(f);
    return (f >= 0.f) ? (b | 0x80000000u) : ~b;
}
__device__ __forceinline__ float dec_f(unsigned u) {
    return (u & 0x80000000u) ? __uint_as_float(u & 0x7FFFFFFFu) : __uint_as_float(~u);
}
// fp32 -> bf16 (round-to-nearest-even)
__device__ __forceinline__ ushort f2bf(float f) {
    unsigned u = __float_as_uint(f);
    unsigned r = u + 0x7FFFu + ((u >> 16) & 1u);
    return (ushort)(r >> 16);
}
// 8 bf16 (16B) fused-multiply-accumulate into fp32 acc[8]
__device__ __forceinline__ void fma8(float* acc, const ushort* p, float w) {
    uint4 q = *(const uint4*)p;
    acc[0] += w * __uint_as_float((q.x & 0xFFFFu) << 16);
    acc[1] += w * __uint_as_float(q.x & 0xFFFF0000u);
    acc[2] += w * __uint_as_float((q.y & 0xFFFFu) << 16);
    acc[3] += w * __uint_as_float(q.y & 0xFFFF0000u);
    acc[4] += w * __uint_as_float((q.z & 0xFFFFu) << 16);
    acc[5] += w * __uint_as_float(q.z & 0xFFFF0000u);
    acc[6] += w * __uint_as_float((q.w & 0xFFFFu) << 16);
    acc[7] += w * __uint_as_float(q.w & 0xFFFF0000u);
}

// ================= CSR build: counting sort w/ precomputed bases =================
__global__ __launch_bounds__(256) void k_bhist(const int* __restrict__ dst,
                                               int* __restrict__ hcnt) {
    __shared__ int lh[NBF];
    for (int i = threadIdx.x; i < NBF; i += 256) lh[i] = 0;
    __syncthreads();
    int e0 = blockIdx.x * CHK;
    for (int e = e0 + threadIdx.x; e < e0 + CHK; e += 256)
        atomicAdd(&lh[dst[e] >> 7], 1);
    __syncthreads();
    int* row = hcnt + (size_t)blockIdx.x * NBF;
    for (int i = threadIdx.x; i < NBF; i += 256) row[i] = lh[i];
}

// per-bin exclusive scan across the GB blocks (in-place), bin totals out
__global__ __launch_bounds__(256) void k_bbase1(int* __restrict__ hcnt,
                                                int* __restrict__ tot) {
    __shared__ int sm[256];
    int bin = blockIdx.x, t = threadIdx.x;
    int v[2];
    int s = 0;
    #pragma unroll
    for (int j = 0; j < 2; ++j) {
        v[j] = hcnt[(size_t)(t * 2 + j) * NBF + bin];
        s += v[j];
    }
    sm[t] = s;
    __syncthreads();
    #pragma unroll
    for (int off = 1; off < 256; off <<= 1) {
        int u = (t >= off) ? sm[t - off] : 0;
        __syncthreads();
        sm[t] += u;
        __syncthreads();
    }
    int run = sm[t] - s;
    if (t == 255) tot[bin] = sm[255];
    #pragma unroll
    for (int j = 0; j < 2; ++j) {
        hcnt[(size_t)(t * 2 + j) * NBF + bin] = run;
        run += v[j];
    }
}

// scan of 625 bin totals -> bo, PLUS bf16 weight prep (merged to save a launch)
__global__ __launch_bounds__(1024) void k_bbase2w(const int* __restrict__ tot,
                                                  int* __restrict__ bo,
                                                  const float* __restrict__ W2,
                                                  const float* __restrict__ W4,
                                                  ushort* __restrict__ W2t,
                                                  ushort* __restrict__ W4t) {
    __shared__ int sm[1024];
    int t = threadIdx.x;
    int v = (t < NBF) ? tot[t] : 0;
    sm[t] = v;
    __syncthreads();
    #pragma unroll
    for (int off = 1; off < 1024; off <<= 1) {
        int u = (t >= off) ? sm[t - off] : 0;
        __syncthreads();
        sm[t] += u;
        __syncthreads();
    }
    if (t < NBF) bo[t] = sm[t] - v;
    if (t == 0) bo[NBF] = NE;
    {
        int f = t >> 5, k = t & 31;
        W2t[t] = f2bf(W2[k * 32 + f]);
    }
    #pragma unroll
    for (int j = 0; j < 4; ++j) {
        int i = t + j * 1024;
        int f = i >> 6, k = i & 63;
        W4t[i] = f2bf(W4[k * 64 + f]);
    }
}

// Pass C: bucket edges. In-LDS counting sort by bucket, then coalesced run
// writes (consecutive lanes -> consecutive addresses within each bucket run).
// No global atomics. Payload: src(17b) | g(3b,@17) | dlow(7b,@20)
__global__ __launch_bounds__(256) void k_bfill(const int* __restrict__ src,
                                               const int* __restrict__ dst,
                                               const float* __restrict__ ew,
                                               const int* __restrict__ ids,
                                               const int* __restrict__ hcnt,
                                               const int* __restrict__ bo,
                                               int2* __restrict__ cB) {
    __shared__ int lh[NBF];       // counts -> per-bin LDS start
    __shared__ int delta[NBF];    // global_base - lds_start per bin
    __shared__ int lcur[NBF];     // scatter cursors
    __shared__ int2 srt[CHK];     // bucket-sorted edges (20 KB)
    __shared__ short sbin[CHK];   // bin tag per sorted slot (5 KB)
    __shared__ int sm[256];
    int t = threadIdx.x;
    int e0 = blockIdx.x * CHK;
    const int* row = hcnt + (size_t)blockIdx.x * NBF;
    for (int i = t; i < NBF; i += 256) lh[i] = 0;
    __syncthreads();
    // phase 1: histogram
    for (int e = e0 + t; e < e0 + CHK; e += 256)
        atomicAdd(&lh[dst[e] >> 7], 1);
    __syncthreads();
    // phase 2: LDS exclusive scan (3 bins/thread) + delta + cursor init
    int c0, c1, c2;
    {
        int i0 = t * 3, i1 = t * 3 + 1, i2 = t * 3 + 2;
        c0 = (i0 < NBF) ? lh[i0] : 0;
        c1 = (i1 < NBF) ? lh[i1] : 0;
        c2 = (i2 < NBF) ? lh[i2] : 0;
    }
    int ssum = c0 + c1 + c2;
    sm[t] = ssum;
    __syncthreads();
    #pragma unroll
    for (int off = 1; off < 256; off <<= 1) {
        int u = (t >= off) ? sm[t - off] : 0;
        __syncthreads();
        sm[t] += u;
        __syncthreads();
    }
    {
        int run = sm[t] - ssum;
        int i0 = t * 3;
        #pragma unroll
        for (int j = 0; j < 3; ++j) {
            int idx = i0 + j;
            int cnt = (j == 0) ? c0 : (j == 1) ? c1 : c2;
            if (idx < NBF) {
                lh[idx] = run;
                delta[idx] = row[idx] + bo[idx] - run;
                lcur[idx] = 0;
            }
            run += cnt;
        }
    }
    __syncthreads();
    // phase 3: scatter into sorted LDS staging
    for (int e = e0 + t; e < e0 + CHK; e += 256) {
        int d = dst[e];
        int s = src[e];
        int bin = d >> 7;
        int r = atomicAdd(&lcur[bin], 1);
        int slot = lh[bin] + r;
        srt[slot] = make_int2(s | (ids[s] << 17) | ((d & 127) << 20),
                              __float_as_int(ew[e]));
        sbin[slot] = (short)bin;
    }
    __syncthreads();
    // phase 4: coalesced run writes
    for (int p = t; p < CHK; p += 256)
        cB[delta[sbin[p]] + p] = srt[p];
}

// Pass D + fused gSX: sort bucket by dlow -> rp,cE; then L2-hot S/AX gather
__global__ __launch_bounds__(512) void k_insort(const int* __restrict__ bo,
                                                const int2* __restrict__ cB,
                                                const float* __restrict__ x,
                                                int* __restrict__ rp,
                                                int2* __restrict__ cE,
                                                float* __restrict__ S,
                                                float* __restrict__ AX) {
    __shared__ int lc[128];
    __shared__ int loff[128];
    __shared__ int sm[512];
    int bin = blockIdx.x, t = threadIdx.x;
    int s0 = bo[bin], s1 = bo[bin + 1];
    if (t < 128) lc[t] = 0;
    __syncthreads();
    for (int i = s0 + t; i < s1; i += 512)
        atomicAdd(&lc[(cB[i].x >> 20) & 127], 1);
    __syncthreads();
    int v = (t < 128) ? lc[t] : 0;
    sm[t] = v;
    __syncthreads();
    #pragma unroll
    for (int off = 1; off < 128; off <<= 1) {
        int u = (t >= off && t < 128) ? sm[t - off] : 0;
        __syncthreads();
        if (t < 128) sm[t] += u;
        __syncthreads();
    }
    if (t < 128) {
        loff[t] = sm[t] - v;
        rp[bin * 128 + t] = s0 + loff[t];
        lc[t] = 0;
    }
    if (bin == NBF - 1 && t == 0) rp[NN] = NE;
    __syncthreads();
    for (int i = s0 + t; i < s1; i += 512) {
        int2 a = cB[i];
        int dlow = (a.x >> 20) & 127;
        int pos = s0 + loff[dlow] + atomicAdd(&lc[dlow], 1);
        cE[pos] = make_int2((a.x & 0x1FFFF) | (((a.x >> 17) & 7) << 24), a.y);
    }
    __syncthreads();
    int n = t >> 2, q = t & 3;
    int ne0 = s0 + loff[n];
    int ne1 = ne0 + lc[n];
    float sv[8] = {0, 0, 0, 0, 0, 0, 0, 0};
    float ax0 = 0.f, ax1 = 0.f, ax2 = 0.f;
    for (int i = ne0 + q; i < ne1; i += 4) {
        int2 a = cE[i];
        float w = __int_as_float(a.y);
        int s = a.x & 0xFFFFFF;
        int gg = a.x >> 24;
        #pragma unroll
        for (int g = 0; g < 8; ++g) sv[g] += (gg == g) ? w : 0.f;
        const float* xp = x + s * 3;
        ax0 += w * xp[0]; ax1 += w * xp[1]; ax2 += w * xp[2];
    }
    #pragma unroll
    for (int g = 0; g < 8; ++g) {
        sv[g] += __shfl_xor(sv[g], 1);
        sv[g] += __shfl_xor(sv[g], 2);
    }
    ax0 += __shfl_xor(ax0, 1); ax0 += __shfl_xor(ax0, 2);
    ax1 += __shfl_xor(ax1, 1); ax1 += __shfl_xor(ax1, 2);
    ax2 += __shfl_xor(ax2, 1); ax2 += __shfl_xor(ax2, 2);
    if (q == 0) {
        int node = bin * 128 + n;
        float4* Sp = (float4*)(S + (size_t)node * 8);
        Sp[0] = make_float4(sv[0], sv[1], sv[2], sv[3]);
        Sp[1] = make_float4(sv[4], sv[5], sv[6], sv[7]);
        *(float4*)(AX + (size_t)node * 4) = make_float4(ax0, ax1, ax2, 0.f);
    }
}

// ======== layer 1+2 fully fused: per-edge on-the-fly h1 from AX (L2-hot),
// aggregate in regs, MFMA @W2 per node, BN+pool epilogue -> MXE1 ========
__global__ __launch_bounds__(256) void k_gpl2(const float* __restrict__ AX,
                                              const float* __restrict__ W1,
                                              const float* __restrict__ b1,
                                              const ushort* __restrict__ W2t,
                                              const int* __restrict__ rp,
                                              const int2* __restrict__ cE,
                                              const int* __restrict__ ids,
                                              const float* __restrict__ b2,
                                              const float* __restrict__ g1,
                                              const float* __restrict__ be1,
                                              const float* __restrict__ m1,
                                              const float* __restrict__ v1,
                                              unsigned* __restrict__ mxe) {
    __shared__ unsigned lmx[NGR * 32];
    __shared__ ushort aggS[64 * 40];
    __shared__ int gids[64];
    int t = threadIdx.x;
    int nb = blockIdx.x * 64;
    lmx[t] = 0u;
    if (t < 64) gids[t] = ids[nb + t];
    int c = t & 3;
    float w1r0[8], w1r1[8], w1r2[8], b1c[8];
    #pragma unroll
    for (int j = 0; j < 8; ++j) {
        int f = c * 8 + j;
        w1r0[j] = W1[f]; w1r1[j] = W1[32 + f]; w1r2[j] = W1[64 + f];
        b1c[j] = b1[f];
    }
    int nl = t >> 2;
    int n = nb + nl;
    int e0 = rp[n], e1 = rp[n + 1];
    float acc[8] = {0, 0, 0, 0, 0, 0, 0, 0};
    for (int i = e0; i < e1; ++i) {
        int2 a = cE[i];
        float w = __int_as_float(a.y);
        float axv = AX[(size_t)(a.x & 0xFFFFFF) * 4 + c];
        float a0 = __shfl(axv, 0, 4);
        float a1 = __shfl(axv, 1, 4);
        float a2 = __shfl(axv, 2, 4);
        #pragma unroll
        for (int j = 0; j < 8; ++j) {
            float pre = b1c[j] + a0 * w1r0[j] + a1 * w1r1[j] + a2 * w1r2[j];
            acc[j] += w * fmaxf(pre, 0.f);
        }
    }
    #pragma unroll
    for (int j = 0; j < 8; ++j) aggS[nl * 40 + c * 8 + j] = f2bf(acc[j]);
    __syncthreads();
    int lane = t & 63, wave = t >> 6;
    int quad = lane >> 4, col = lane & 15;
    bf16x8 afr = *(const bf16x8*)(aggS + (wave * 16 + col) * 40 + quad * 8);
    #pragma unroll
    for (int nt = 0; nt < 2; ++nt) {
        bf16x8 bfr = *(const bf16x8*)(W2t + (nt * 16 + col) * 32 + quad * 8);
        f32x4 d = {0.f, 0.f, 0.f, 0.f};
        d = __builtin_amdgcn_mfma_f32_16x16x32_bf16(afr, bfr, d, 0, 0, 0);
        int f = nt * 16 + col;
        float scale = g1[f] * rsqrtf(v1[f] + BN_EPS);
        float bb = b2[f], mm = m1[f], bee = be1[f];
        #pragma unroll
        for (int r = 0; r < 4; ++r) {
            int node_l = wave * 16 + quad * 4 + r;
            float h = fmaxf(d[r] + bb, 0.f);
            float val = (h - mm) * scale + bee;
            atomicMax(&lmx[gids[node_l] * 32 + f], enc_f(val));
        }
    }
    __syncthreads();
    {
        unsigned u = lmx[t];
        if (u) atomicMax(&mxe[t], u);
    }
}

// ======== MFMA fused l3+l4 (+ integrated dechw3):
// HW3 = dec(MXE1)@W3 per block; tmp4 = bf16(relu(S@HW3+b3))@bf16(W4) -> T ========
__global__ __launch_bounds__(256) void k_l34m(const float* __restrict__ S,
                                              const unsigned* __restrict__ mxe,
                                              const float* __restrict__ W3,
                                              const float* __restrict__ b3,
                                              const ushort* __restrict__ W4t,
                                              ushort* __restrict__ T) {
    __shared__ float smxs[256];
    __shared__ float HW3s[512];
    __shared__ ushort h3s[64 * 72];
    int t = threadIdx.x;
    int nb = blockIdx.x * 64;
    smxs[t] = mxe[t] ? dec_f(mxe[t]) : 0.f;
    __syncthreads();
    {
        #pragma unroll
        for (int j = 0; j < 2; ++j) {
            int i = t + j * 256;
            int g = i >> 6, f = i & 63;
            float acc = 0.f;
            #pragma unroll
            for (int k = 0; k < 32; ++k) acc += smxs[g * 32 + k] * W3[k * 64 + f];
            HW3s[i] = acc;
        }
    }
    __syncthreads();
    {
        int f = t & 63, rr = t >> 6;
        float hwc[8];
        #pragma unroll
        for (int g = 0; g < 8; ++g) hwc[g] = HW3s[g * 64 + f];
        float bb = b3[f];
        #pragma unroll
        for (int i = 0; i < 16; ++i) {
            int n = rr + i * 4;
            const float4* sp = (const float4*)(S + (size_t)(nb + n) * 8);
            float4 s0 = sp[0], s1 = sp[1];
            float acc = bb + s0.x * hwc[0] + s0.y * hwc[1] + s0.z * hwc[2] +
                        s0.w * hwc[3] + s1.x * hwc[4] + s1.y * hwc[5] +
                        s1.z * hwc[6] + s1.w * hwc[7];
            h3s[n * 72 + f] = f2bf(fmaxf(acc, 0.f));
        }
    }
    __syncthreads();
    int lane = t & 63, wave = t >> 6;
    int quad = lane >> 4, col = lane & 15;
    int mtile = wave;
    bf16x8 a0 = *(const bf16x8*)(h3s + (mtile * 16 + col) * 72 + quad * 8);
    bf16x8 a1 = *(const bf16x8*)(h3s + (mtile * 16 + col) * 72 + 32 + quad * 8);
    #pragma unroll
    for (int ntile = 0; ntile < 4; ++ntile) {
        bf16x8 b0 = *(const bf16x8*)(W4t + (ntile * 16 + col) * 64 + quad * 8);
        bf16x8 b1v = *(const bf16x8*)(W4t + (ntile * 16 + col) * 64 + 32 + quad * 8);
        f32x4 acc = {0.f, 0.f, 0.f, 0.f};
        acc = __builtin_amdgcn_mfma_f32_16x16x32_bf16(a0, b0, acc, 0, 0, 0);
        acc = __builtin_amdgcn_mfma_f32_16x16x32_bf16(a1, b1v, acc, 0, 0, 0);
        #pragma unroll
        for (int r = 0; r < 4; ++r) {
            int node = nb + mtile * 16 + quad * 4 + r;
            T[node * 64 + ntile * 16 + col] = f2bf(acc[r]);
        }
    }
}

// ---- fused gather (bf16 rows) + bias + relu + BN + per-graph max pool ----
template <int LOGF>
__global__ __launch_bounds__(256) void k_gpool(const ushort* __restrict__ th,
                                               const int* __restrict__ rp,
                                               const int2* __restrict__ cE,
                                               const int* __restrict__ ids,
                                               const float* __restrict__ b,
                                               const float* __restrict__ g,
                                               const float* __restrict__ be,
                                               const float* __restrict__ m,
                                               const float* __restrict__ v,
                                               unsigned* __restrict__ mxe) {
    const int F = 1 << LOGF;
    const int CPN = F >> 3;
    const int NPB = 256 / CPN;
    __shared__ unsigned lmx[NGR * F];
    for (int i = threadIdx.x; i < NGR * F; i += 256) lmx[i] = 0u;
    __syncthreads();
    int c = threadIdx.x & (CPN - 1);
    int n = blockIdx.x * NPB + (threadIdx.x >> (LOGF - 3));
    if (n < NN) {
        int e0 = rp[n], e1 = rp[n + 1];
        float a0[8] = {0, 0, 0, 0, 0, 0, 0, 0};
        float a1[8] = {0, 0, 0, 0, 0, 0, 0, 0};
        float a2[8] = {0, 0, 0, 0, 0, 0, 0, 0};
        float a3[8] = {0, 0, 0, 0, 0, 0, 0, 0};
        int i = e0;
        for (; i + 4 <= e1; i += 4) {
            int2 q0 = cE[i], q1 = cE[i + 1], q2 = cE[i + 2], q3 = cE[i + 3];
            fma8(a0, th + (((size_t)(q0.x & 0xFFFFFF)) << LOGF) + (c << 3), __int_as_float(q0.y));
            fma8(a1, th + (((size_t)(q1.x & 0xFFFFFF)) << LOGF) + (c << 3), __int_as_float(q1.y));
            fma8(a2, th + (((size_t)(q2.x & 0xFFFFFF)) << LOGF) + (c << 3), __int_as_float(q2.y));
            fma8(a3, th + (((size_t)(q3.x & 0xFFFFFF)) << LOGF) + (c << 3), __int_as_float(q3.y));
        }
        for (; i < e1; ++i) {
            int2 q0 = cE[i];
            fma8(a0, th + (((size_t)(q0.x & 0xFFFFFF)) << LOGF) + (c << 3), __int_as_float(q0.y));
        }
        int gg = ids[n];
        #pragma unroll
        for (int j = 0; j < 8; ++j) {
            int f = (c << 3) + j;
            float scale = g[f] * rsqrtf(v[f] + BN_EPS);
            float h = fmaxf((a0[j] + a1[j]) + (a2[j] + a3[j]) + b[f], 0.f);
            float val = (h - m[f]) * scale + be[f];
            atomicMax(&lmx[gg * F + f], enc_f(val));
        }
    }
    __syncthreads();
    for (int i = threadIdx.x; i < NGR * F; i += 256) {
        unsigned u = lmx[i];
        if (u) atomicMax(&mxe[i], u);
    }
}

// ---- out = softmax(S @ (dec(MXE2)@W5) + b5), HW5 computed per block ----
__global__ __launch_bounds__(256) void k_out(const float* __restrict__ S,
                                             const unsigned* __restrict__ mxe,
                                             const float* __restrict__ W5,
                                             const float* __restrict__ b5,
                                             float* __restrict__ out) {
    __shared__ float smxs[512];
    __shared__ float hw[160];
    __shared__ float bb[20];
    int t = threadIdx.x;
    smxs[t] = mxe[t] ? dec_f(mxe[t]) : 0.f;
    smxs[t + 256] = mxe[t + 256] ? dec_f(mxe[t + 256]) : 0.f;
    if (t < 20) bb[t] = b5[t];
    __syncthreads();
    if (t < 160) {
        int g = t / 20, c = t % 20;
        float acc = 0.f;
        #pragma unroll
        for (int k = 0; k < 64; ++k) acc += smxs[g * 64 + k] * W5[k * 20 + c];
        hw[t] = acc;
    }
    __syncthreads();
    int n = blockIdx.x * 256 + t;
    if (n >= NN) return;
    const float4* sp = (const float4*)(S + (size_t)n * 8);
    float4 s0 = sp[0], s1 = sp[1];
    float sv[8] = {s0.x, s0.y, s0.z, s0.w, s1.x, s1.y, s1.z, s1.w};
    float pre[20];
    #pragma unroll
    for (int c = 0; c < 20; ++c) {
        float acc = bb[c];
        #pragma unroll
        for (int g = 0; g < 8; ++g) acc += sv[g] * hw[g * 20 + c];
        pre[c] = acc;
    }
    float mx = pre[0];
    #pragma unroll
    for (int c = 1; c < 20; ++c) mx = fmaxf(mx, pre[c]);
    float sum = 0.f;
    #pragma unroll
    for (int c = 0; c < 20; ++c) { pre[c] = __expf(pre[c] - mx); sum += pre[c]; }
    float inv = 1.f / sum;
    #pragma unroll
    for (int c = 0; c < 20; ++c) out[n * 20 + c] = pre[c] * inv;
}

extern "C" void kernel_launch(void* const* d_in, const int* in_sizes, int n_in,
                              void* d_out, int out_size, void* d_ws, size_t ws_size,
                              hipStream_t stream) {
    const float* x   = (const float*)d_in[0];
    const float* ew  = (const float*)d_in[1];
    const int*   src = (const int*)d_in[2];
    const int*   dst = (const int*)d_in[3];
    const int*   ids = (const int*)d_in[4];
    const float* W1 = (const float*)d_in[5];  const float* b1 = (const float*)d_in[6];
    const float* W2 = (const float*)d_in[7];  const float* b2 = (const float*)d_in[8];
    const float* g1 = (const float*)d_in[9];  const float* be1 = (const float*)d_in[10];
    const float* m1 = (const float*)d_in[11]; const float* v1 = (const float*)d_in[12];
    const float* W3 = (const float*)d_in[13]; const float* b3 = (const float*)d_in[14];
    const float* W4 = (const float*)d_in[15]; const float* b4 = (const float*)d_in[16];
    const float* g2 = (const float*)d_in[17]; const float* be2 = (const float*)d_in[18];
    const float* m2 = (const float*)d_in[19]; const float* v2 = (const float*)d_in[20];
    const float* W5 = (const float*)d_in[21]; const float* b5 = (const float*)d_in[22];
    float* out = (float*)d_out;

    // workspace layout (~36 MB)
    char* p = (char*)d_ws;
    float*  S    = (float*)p;  p += (size_t)NN * 8 * 4;
    ushort* T    = (ushort*)p; p += (size_t)NN * 64 * 2;     // tmp4 (bf16)
    float*  AX   = (float*)p;  p += (size_t)NN * 4 * 4;
    int*    rp   = (int*)p;    p += (size_t)(NN + 16) * 4;
    int*    hcnt = (int*)p;    p += (size_t)GB * NBF * 4;    // 1.28 MB
    int*    tot  = (int*)p;    p += 1024 * 4;
    int*    bo   = (int*)p;    p += 1024 * 4;
    int2*   cB   = (int2*)p;   p += (size_t)NE * 8;
    int2*   cE   = (int2*)p;   p += (size_t)NE * 8;
    unsigned* MXE1 = (unsigned*)p; p += 256 * 4;
    unsigned* MXE2 = (unsigned*)p; p += 512 * 4;             // contiguous w/ MXE1
    ushort* W2t  = (ushort*)p; p += 1024 * 2;
    ushort* W4t  = (ushort*)p; p += 4096 * 2;

    const int BS = 256;
    const int gN = (NN + BS - 1) / BS;

    // ---- CSR build (no global atomics) ----
    hipMemsetAsync(MXE1, 0, 768 * 4, stream);
    hipLaunchKernelGGL(k_bhist, dim3(GB), dim3(BS), 0, stream, dst, hcnt);
    hipLaunchKernelGGL(k_bbase1, dim3(NBF), dim3(BS), 0, stream, hcnt, tot);
    hipLaunchKernelGGL(k_bbase2w, dim3(1), dim3(1024), 0, stream, tot, bo, W2, W4, W2t, W4t);
    hipLaunchKernelGGL(k_bfill, dim3(GB), dim3(BS), 0, stream, src, dst, ew, ids, hcnt, bo, cB);
    hipLaunchKernelGGL(k_insort, dim3(NBF), dim3(512), 0, stream, bo, cB, x, rp, cE, S, AX);

    // ---- layers 1+2 fully fused -> MXE1 ----
    hipLaunchKernelGGL(k_gpl2, dim3(NN / 64), dim3(BS), 0, stream, AX, W1, b1, W2t,
                       rp, cE, ids, b2, g1, be1, m1, v1, MXE1);

    // ---- layers 3+4 (MFMA, dechw3 integrated): tmp4(T) = relu(S@HW3+b3)@W4 ----
    hipLaunchKernelGGL(k_l34m, dim3(NN / 64), dim3(BS), 0, stream, S, MXE1, W3, b3, W4t, T);
    hipLaunchKernelGGL(k_gpool<6>, dim3(NN / 32), dim3(BS), 0, stream, T, rp, cE, ids, b4, g2, be2, m2, v2, MXE2);

    // ---- layer 5 (collapsed, dechw5 integrated): out = softmax(S@HW5+b5) ----
    hipLaunchKernelGGL(k_out, dim3(gN), dim3(BS), 0, stream, S, MXE2, W5, b5, out);
}